// Round 1
// baseline (2580.978 us; speedup 1.0000x reference)
//
#include <hip/hip_runtime.h>
#include <hip/hip_bf16.h>
#include <math.h>

// Problem constants
#define PB 8
constexpr int B_   = 4;
constexpr int CIN  = 96;
constexpr int H_   = 256;
constexpr int W_   = 256;
constexpr int HID  = 192;
constexpr int C2   = 384;           // HID*2
constexpr int HP   = H_ / PB;       // 32
constexpr int WP   = W_ / PB;       // 32

// ---------------------------------------------------------------------------
// Kernel 0a: build the per-channel 8x8 spatial gate kernel g_c from fft_w.
// irfft2(rfft2(x) * W) == circular conv of the 8x8 patch with
// g = IDFT2(G_eff), where G_eff is the Hermitian completion of the half
// spectrum W (cols 0 and 4 symmetrized, matching irfft's Re() treatment).
// Also flags channels where g is exactly the delta kernel (identity gate).
// ---------------------------------------------------------------------------
__global__ void prep_gate(const float* __restrict__ fftw,
                          float* __restrict__ g, int* __restrict__ flags) {
    int c = blockIdx.x;          // 0..383
    int t = threadIdx.x;         // 0..63 (one wave)
    int n1 = t >> 3, n2 = t & 7;
    const float* Wc = fftw + c * 40;   // [8][5]
    const double ct[8] = {1.0, 0.70710678118654752, 0.0, -0.70710678118654752,
                          -1.0, -0.70710678118654752, 0.0, 0.70710678118654752};
    double acc = 0.0;
    for (int k1 = 0; k1 < 8; ++k1) {
        for (int k2 = 0; k2 < 8; ++k2) {
            double geff;
            if (k2 == 0 || k2 == 4) {
                geff = 0.5 * ((double)Wc[k1 * 5 + k2] +
                              (double)Wc[((8 - k1) & 7) * 5 + k2]);
            } else if (k2 < 4) {
                geff = (double)Wc[k1 * 5 + k2];
            } else {
                geff = (double)Wc[((8 - k1) & 7) * 5 + (8 - k2)];
            }
            acc += geff * ct[(k1 * n1 + k2 * n2) & 7];
        }
    }
    acc *= (1.0 / 64.0);
    g[c * 64 + t] = (float)acc;
    double expect = (t == 0) ? 1.0 : 0.0;
    bool ok = fabs(acc - expect) <= 1e-6;
    unsigned long long m = __ballot(ok);
    if (t == 0) flags[c] = (m == 0xFFFFFFFFFFFFFFFFull) ? 1 : 0;
}

// ---------------------------------------------------------------------------
// Kernel 0b: transpose weights for wave-uniform contiguous scalar loads.
//   wt  [192][96]  = w_out^T   (w_out is [96][192])
//   wint[96][384]  = w_in^T    (w_in  is [384][96])
// ---------------------------------------------------------------------------
__global__ void prep_transpose(const float* __restrict__ w_out,
                               const float* __restrict__ w_in,
                               float* __restrict__ wt,
                               float* __restrict__ wint) {
    int idx = blockIdx.x * 256 + threadIdx.x;
    if (idx < HID * CIN) {                 // 18432
        int c = idx / CIN, o = idx % CIN;
        wt[idx] = w_out[o * HID + c];
    }
    int j = idx - HID * CIN;
    if (j >= 0 && j < CIN * C2) {          // 36864
        int k = j / C2, oc = j % C2;
        wint[j] = w_in[oc * CIN + k];
    }
}

// ---------------------------------------------------------------------------
// Kernel A: fused GEMM1 (1x1 conv 96->384) + spectral gate, per 8x8 patch.
// Block = 256 threads = 4 waves; each wave owns 24 output channels x 64 px.
// One block handles one patch x one 96-channel group (cg in 0..3).
// Writes gated z for a single batch as bf16.
// ---------------------------------------------------------------------------
__global__ __launch_bounds__(256)
void gemm1_gate(const float* __restrict__ x, const float* __restrict__ wint,
                const float* __restrict__ g, const int* __restrict__ flags,
                __hip_bfloat16* __restrict__ z, int b) {
    __shared__ float xs[CIN][64];
    __shared__ float ys[CIN][64];
    int t = threadIdx.x;
    int bid = blockIdx.x;                 // 4096 = 32*32*4
    int cg = bid & 3;
    int pw = (bid >> 2) & 31;
    int ph = bid >> 7;
    int row0 = ph * PB, col0 = pw * PB;
    int p = t & 63, wv = t >> 6;
    int p1 = p >> 3, p2 = p & 7;

    // stage input patch: x[b, 0..95, row0:+8, col0:+8]
    for (int i = t; i < CIN * 64; i += 256) {
        int k = i >> 6, pp = i & 63;
        xs[k][pp] = x[((size_t)(b * CIN + k) * H_ + (row0 + (pp >> 3))) * W_ +
                      col0 + (pp & 7)];
    }
    __syncthreads();

    float acc[24];
#pragma unroll
    for (int j = 0; j < 24; ++j) acc[j] = 0.f;
    int jbase = wv * 24;
    int ocbase = cg * 96 + jbase;
#pragma unroll 4
    for (int k = 0; k < CIN; ++k) {
        float xv = xs[k][p];
        const float* wr = wint + k * C2 + ocbase;   // wave-uniform, contiguous
#pragma unroll
        for (int j = 0; j < 24; ++j) acc[j] += wr[j] * xv;
    }
#pragma unroll
    for (int j = 0; j < 24; ++j) ys[jbase + j][p] = acc[j];
    __syncthreads();

    // spectral gate: per-channel circular conv within the 8x8 patch
    for (int j = 0; j < 24; ++j) {
        int cl = jbase + j;
        int c = cg * 96 + cl;
        float v;
        if (flags[c]) {              // identity gate (fft_w row is all-pass)
            v = ys[cl][p];
        } else {
            const float* gc = g + c * 64;
            float s = 0.f;
            for (int q1 = 0; q1 < 8; ++q1)
                for (int q2 = 0; q2 < 8; ++q2)
                    s += ys[cl][q1 * 8 + q2] *
                         gc[((p1 - q1) & 7) * 8 + ((p2 - q2) & 7)];
            v = s;
        }
        z[(size_t)((c * H_ + row0 + p1) * W_ + col0 + p2)] = __float2bfloat16(v);
    }
}

// ---------------------------------------------------------------------------
// Kernel B: fused depthwise 3x3 + exact-erf GELU gating + GEMM2 (192->96).
// Block = 256 threads, one 16x16 output tile, one pixel per thread.
// Double-buffered LDS staging of the 18x18 halo for channel pair (c, c+192).
// acc[96] output channels held in VGPRs per thread.
// ---------------------------------------------------------------------------
__global__ __launch_bounds__(256)
void dw_gelu_gemm2(const __hip_bfloat16* __restrict__ z,
                   const float* __restrict__ w_dw,
                   const float* __restrict__ wt,
                   float* __restrict__ out, int b) {
    __shared__ float s1[2][18][19];
    __shared__ float s2[2][18][19];
    int t = threadIdx.x;
    int lx = t & 15, ly = t >> 4;
    int gx = blockIdx.x * 16 + lx, gy = blockIdx.y * 16 + ly;
    int x0 = blockIdx.x * 16 - 1, y0 = blockIdx.y * 16 - 1;

    auto stage = [&](int c, int bi) {
        const __hip_bfloat16* zc1 = z + (size_t)c * (H_ * W_);
        const __hip_bfloat16* zc2 = z + (size_t)(c + HID) * (H_ * W_);
        for (int i = t; i < 324; i += 256) {
            int r = i / 18, cc = i - r * 18;
            int yy = y0 + r, xx = x0 + cc;
            bool ok = (yy >= 0) && (yy < H_) && (xx >= 0) && (xx < W_);
            size_t off = (size_t)(yy * W_ + xx);
            float v1 = ok ? __bfloat162float(zc1[off]) : 0.f;
            float v2 = ok ? __bfloat162float(zc2[off]) : 0.f;
            s1[bi][r][cc] = v1;
            s2[bi][r][cc] = v2;
        }
    };

    float acc[96];
#pragma unroll
    for (int o = 0; o < 96; ++o) acc[o] = 0.f;

    stage(0, 0);
    for (int c = 0; c < HID; ++c) {
        int cur = c & 1;
        __syncthreads();                  // buf[cur] ready; buf[cur^1] free
        if (c < HID - 1) stage(c + 1, cur ^ 1);
        const float* wd1 = w_dw + c * 9;
        const float* wd2 = w_dw + (c + HID) * 9;
        float d1 = 0.f, d2 = 0.f;
#pragma unroll
        for (int dy = 0; dy < 3; ++dy)
#pragma unroll
            for (int dx = 0; dx < 3; ++dx) {
                d1 += s1[cur][ly + dy][lx + dx] * wd1[dy * 3 + dx];
                d2 += s2[cur][ly + dy][lx + dx] * wd2[dy * 3 + dx];
            }
        float tg = 0.5f * d1 * (1.f + erff(d1 * 0.70710678118654752f)) * d2;
        const float* wo = wt + c * CIN;   // uniform, contiguous -> s_load
#pragma unroll
        for (int o = 0; o < 96; ++o) acc[o] += wo[o] * tg;
    }
    size_t obase = (size_t)(b * CIN) * (H_ * W_) + (size_t)gy * W_ + gx;
#pragma unroll
    for (int o = 0; o < 96; ++o)
        out[obase + (size_t)o * (H_ * W_)] = acc[o];
}

// ---------------------------------------------------------------------------
extern "C" void kernel_launch(void* const* d_in, const int* in_sizes, int n_in,
                              void* d_out, int out_size, void* d_ws, size_t ws_size,
                              hipStream_t stream) {
    const float* x     = (const float*)d_in[0];
    const float* w_in  = (const float*)d_in[1];
    const float* w_dw  = (const float*)d_in[2];
    const float* fftw  = (const float*)d_in[3];
    const float* w_out = (const float*)d_in[4];
    float* out = (float*)d_out;

    char* ws = (char*)d_ws;
    float* g      = (float*)(ws);                 //  98304 B
    int*   flags  = (int*)  (ws + 98304);         //   1536 B
    float* wt     = (float*)(ws + 102400);        //  73728 B (w_out^T)
    float* wint   = (float*)(ws + 176128);        // 147456 B (w_in^T)
    __hip_bfloat16* z = (__hip_bfloat16*)(ws + 327680);  // 50331648 B (one batch)

    prep_gate<<<dim3(C2), dim3(64), 0, stream>>>(fftw, g, flags);
    prep_transpose<<<dim3(216), dim3(256), 0, stream>>>(w_out, w_in, wt, wint);

    for (int b = 0; b < B_; ++b) {
        gemm1_gate<<<dim3(HP * WP * 4), dim3(256), 0, stream>>>(
            x, wint, g, flags, z, b);
        dw_gelu_gemm2<<<dim3(WP / 2, HP / 2), dim3(256), 0, stream>>>(
            z, w_dw, wt, out, b);
    }
}

// Round 2
// 512.003 us; speedup vs baseline: 5.0409x; 5.0409x over previous
//
#include <hip/hip_runtime.h>
#include <hip/hip_bf16.h>
#include <math.h>

typedef short bf16x8 __attribute__((ext_vector_type(8)));
typedef float f32x4  __attribute__((ext_vector_type(4)));

constexpr int B_=4, CIN=96, H_=256, W_=256, HID=192, C2=384;
constexpr int NPX = H_*W_;          // 65536 px per (b,c) plane
#define PB 8
constexpr int HP = H_/PB, WP = W_/PB;

__device__ __forceinline__ ushort f2bf(float f) {
    __hip_bfloat16 h = __float2bfloat16(f);
    ushort u; __builtin_memcpy(&u, &h, 2); return u;
}
__device__ __forceinline__ float bf2f(ushort u) {
    __hip_bfloat16 h; __builtin_memcpy(&h, &u, 2); return __bfloat162float(h);
}

// ---------------------------------------------------------------------------
// prep_gate: per-channel 8x8 spatial gate kernel from fft_w (+identity flags).
// ---------------------------------------------------------------------------
__global__ void prep_gate(const float* __restrict__ fftw,
                          float* __restrict__ g, int* __restrict__ flags) {
    int c = blockIdx.x;
    int t = threadIdx.x;             // one wave
    int n1 = t >> 3, n2 = t & 7;
    const float* Wc = fftw + c * 40;
    const double ct[8] = {1.0, 0.70710678118654752, 0.0, -0.70710678118654752,
                          -1.0, -0.70710678118654752, 0.0, 0.70710678118654752};
    double acc = 0.0;
    for (int k1 = 0; k1 < 8; ++k1)
        for (int k2 = 0; k2 < 8; ++k2) {
            double geff;
            if (k2 == 0 || k2 == 4)
                geff = 0.5 * ((double)Wc[k1*5+k2] + (double)Wc[((8-k1)&7)*5+k2]);
            else if (k2 < 4) geff = (double)Wc[k1*5+k2];
            else             geff = (double)Wc[((8-k1)&7)*5 + (8-k2)];
            acc += geff * ct[(k1*n1 + k2*n2) & 7];
        }
    acc *= (1.0/64.0);
    g[c*64 + t] = (float)acc;
    double expect = (t == 0) ? 1.0 : 0.0;
    unsigned long long m = __ballot(fabs(acc - expect) <= 1e-6);
    if (t == 0) flags[c] = (m == 0xFFFFFFFFFFFFFFFFull) ? 1 : 0;
}

// ---------------------------------------------------------------------------
// prep_w: split weights into bf16 hi + lo (residual) pairs.
//   w_in [384][96] row-major (oc,k); w_out [96][192] row-major (oc,c)
// ---------------------------------------------------------------------------
__global__ void prep_w(const float* __restrict__ w_in, const float* __restrict__ w_out,
                       ushort* __restrict__ whi_in,  ushort* __restrict__ wlo_in,
                       ushort* __restrict__ whi_out, ushort* __restrict__ wlo_out) {
    int idx = blockIdx.x * 256 + threadIdx.x;
    if (idx < C2*CIN) {
        float v = w_in[idx];
        ushort h = f2bf(v);
        whi_in[idx] = h;
        wlo_in[idx] = f2bf(v - bf2f(h));
    }
    int j = idx - C2*CIN;
    if (j >= 0 && j < CIN*HID) {
        float v = w_out[j];
        ushort h = f2bf(v);
        whi_out[j] = h;
        wlo_out[j] = f2bf(v - bf2f(h));
    }
}

// ---------------------------------------------------------------------------
// A1: GEMM1 via MFMA 16x16x32 bf16.  z[c][px] = sum_k w_in[c][k] * x[k][px]
// Block: 256 thr / 4 waves; wave w owns oc in [96w,96w+96); block owns 64 px.
// B-fragments built from global x (fp32->bf16) in registers.
// A = (whi + wlo) split -> 2 MFMAs, removes weight-rounding error.
// ---------------------------------------------------------------------------
__global__ __launch_bounds__(256)
void gemm1_mfma(const float* __restrict__ x,
                const ushort* __restrict__ whi, const ushort* __restrict__ wlo,
                __hip_bfloat16* __restrict__ z, int b) {
    int t = threadIdx.x;
    int l = t & 63, wv = t >> 6;
    int lm = l & 15, g4 = l >> 4;
    int px0 = blockIdx.x * 64;
    const float* xb = x + (size_t)b * CIN * NPX;

    f32x4 acc[6][4];
#pragma unroll
    for (int mf = 0; mf < 6; ++mf)
#pragma unroll
        for (int nf = 0; nf < 4; ++nf) acc[mf][nf] = (f32x4){0.f,0.f,0.f,0.f};

#pragma unroll
    for (int kc = 0; kc < 3; ++kc) {
        int k0 = kc*32 + g4*8;
        bf16x8 bfr[4];
#pragma unroll
        for (int nf = 0; nf < 4; ++nf) {
            const float* xp = xb + (size_t)k0 * NPX + px0 + nf*16 + lm;
            bf16x8 v;
#pragma unroll
            for (int j = 0; j < 8; ++j) v[j] = (short)f2bf(xp[(size_t)j * NPX]);
            bfr[nf] = v;
        }
#pragma unroll
        for (int mf = 0; mf < 6; ++mf) {
            int row = wv*96 + mf*16 + lm;
            bf16x8 ah = *(const bf16x8*)(whi + (size_t)row*CIN + k0);
            bf16x8 al = *(const bf16x8*)(wlo + (size_t)row*CIN + k0);
#pragma unroll
            for (int nf = 0; nf < 4; ++nf) {
                acc[mf][nf] = __builtin_amdgcn_mfma_f32_16x16x32_bf16(ah, bfr[nf], acc[mf][nf], 0,0,0);
                acc[mf][nf] = __builtin_amdgcn_mfma_f32_16x16x32_bf16(al, bfr[nf], acc[mf][nf], 0,0,0);
            }
        }
    }
    // C/D layout: col = lane&15, row = (lane>>4)*4 + r   [verified m89]
#pragma unroll
    for (int mf = 0; mf < 6; ++mf)
#pragma unroll
        for (int nf = 0; nf < 4; ++nf)
#pragma unroll
            for (int r = 0; r < 4; ++r) {
                int c = wv*96 + mf*16 + g4*4 + r;
                z[(size_t)c * NPX + px0 + nf*16 + lm] =
                    __float2bfloat16(acc[mf][nf][r]);
            }
}

// ---------------------------------------------------------------------------
// A2: spectral-gate fixup. No-op when all flags==1 (fft_w == ones).
// General path: per-patch circular conv via __shfl across the 64-px patch.
// ---------------------------------------------------------------------------
__global__ __launch_bounds__(256)
void gate_fix(__hip_bfloat16* __restrict__ z, const float* __restrict__ g,
              const int* __restrict__ flags) {
    int pid = blockIdx.x;            // 0..1023 patches
    int ph = pid >> 5, pw = pid & 31;
    int t = threadIdx.x, l = t & 63, wv = t >> 6;
    int p1 = l >> 3, p2 = l & 7;
    size_t base = (size_t)(ph*8) * W_ + pw*8;
    for (int c = wv; c < C2; c += 4) {
        if (flags[c]) continue;
        const float* gc = g + c*64;
        size_t zi = (size_t)c * NPX + base + (size_t)p1 * W_ + p2;
        float v = __bfloat162float(z[zi]);
        float s = 0.f;
        for (int q = 0; q < 64; ++q) {
            float vq = __shfl(v, q, 64);
            s += vq * gc[((p1 - (q >> 3)) & 7)*8 + ((p2 - (q & 7)) & 7)];
        }
        z[zi] = __float2bfloat16(s);
    }
}

// ---------------------------------------------------------------------------
// B1: depthwise 3x3 + exact-erf GELU gating.  Writes t_g in MFMA-B-fragment
// layout: tgf[panel_rel][kc][lane][8 bf16] (16B per lane), panel = 16 px.
// Grid: (16*(rows/16), 4 channel-splits); block = 16x16 px tile, 48 ch pairs.
// ---------------------------------------------------------------------------
__global__ __launch_bounds__(256)
void dw_gelu(const __hip_bfloat16* __restrict__ z, const float* __restrict__ w_dw,
             ushort* __restrict__ tgf, int r0) {
    __shared__ float s1[2][18][20];
    __shared__ float s2[2][18][20];
    int t = threadIdx.x;
    int lx = t & 15, ly = t >> 4;
    int tx = blockIdx.x & 15, tyr = blockIdx.x >> 4;
    int s = blockIdx.y;              // channel split 0..3
    int x0 = tx*16, y0 = r0 + tyr*16;
    int gy = y0 + ly;
    int xh = x0 - 1, yh = y0 - 1;
    int panel_rel = (gy - r0)*16 + tx;

    auto stage = [&](int c, int bi) {
        const __hip_bfloat16* zc1 = z + (size_t)c * NPX;
        const __hip_bfloat16* zc2 = z + (size_t)(c + HID) * NPX;
        for (int i = t; i < 324; i += 256) {
            int r = i / 18, cc = i - r*18;
            int yy = yh + r, xx = xh + cc;
            bool ok = (yy >= 0) && (yy < H_) && (xx >= 0) && (xx < W_);
            size_t off = (size_t)yy * W_ + xx;
            s1[bi][r][cc] = ok ? __bfloat162float(zc1[off]) : 0.f;
            s2[bi][r][cc] = ok ? __bfloat162float(zc2[off]) : 0.f;
        }
    };

    stage(s*48, 0);
    uint pack[4] = {0,0,0,0};
    for (int i = 0; i < 48; ++i) {
        int c = s*48 + i;
        int cur = i & 1;
        __syncthreads();
        if (i < 47) stage(c + 1, cur ^ 1);
        const float* wd1 = w_dw + c*9;
        const float* wd2 = w_dw + (c + HID)*9;
        float d1 = 0.f, d2 = 0.f;
#pragma unroll
        for (int dy = 0; dy < 3; ++dy)
#pragma unroll
            for (int dx = 0; dx < 3; ++dx) {
                d1 += s1[cur][ly+dy][lx+dx] * wd1[dy*3+dx];
                d2 += s2[cur][ly+dy][lx+dx] * wd2[dy*3+dx];
            }
        float v = 0.5f * d1 * (1.f + erff(d1 * 0.70710678118654752f)) * d2;
        ushort u = f2bf(v);
        int jj = i & 7;
        if ((jj & 1) == 0) pack[jj >> 1] = (uint)u;
        else               pack[jj >> 1] |= ((uint)u) << 16;
        if (jj == 7) {
            int c0 = c - 7;
            int kc = c0 >> 5, gg = (c0 & 31) >> 3;
            uint4 val; val.x = pack[0]; val.y = pack[1]; val.z = pack[2]; val.w = pack[3];
            *(uint4*)(tgf + (size_t)(((panel_rel*6 + kc)*64) + gg*16 + lx) * 8) = val;
        }
    }
}

// ---------------------------------------------------------------------------
// B2: GEMM2 via MFMA.  out[oc][px] = sum_c w_out[oc][c] * t_g[c][px]
// Block: 256 thr / 4 waves; wave owns 64 px of row h; M-split 2-way via
// blockIdx.y (oc 0..47 / 48..95).  B-frags: single coalesced 16B/lane loads
// from tgf fragment layout.  A split hi/lo.
// ---------------------------------------------------------------------------
__global__ __launch_bounds__(256)
void gemm2_mfma(const ushort* __restrict__ tgf,
                const ushort* __restrict__ whi, const ushort* __restrict__ wlo,
                float* __restrict__ out, int b, int r0) {
    int t = threadIdx.x;
    int l = t & 63, wv = t >> 6;
    int lm = l & 15, g4 = l >> 4;
    int h = r0 + blockIdx.x;
    int ms = blockIdx.y;             // 0/1 -> oc base 0/48
    int px0 = h * W_ + wv*64;
    int prel0 = (h - r0)*16 + wv*4;

    f32x4 acc[3][4];
#pragma unroll
    for (int mf = 0; mf < 3; ++mf)
#pragma unroll
        for (int nf = 0; nf < 4; ++nf) acc[mf][nf] = (f32x4){0.f,0.f,0.f,0.f};

#pragma unroll
    for (int kc = 0; kc < 6; ++kc) {
        bf16x8 bfr[4];
#pragma unroll
        for (int nf = 0; nf < 4; ++nf)
            bfr[nf] = *(const bf16x8*)(tgf + (size_t)(((prel0+nf)*6 + kc)*64 + l) * 8);
        int k0 = kc*32 + g4*8;
#pragma unroll
        for (int mf = 0; mf < 3; ++mf) {
            int row = ms*48 + mf*16 + lm;
            bf16x8 ah = *(const bf16x8*)(whi + (size_t)row*HID + k0);
            bf16x8 al = *(const bf16x8*)(wlo + (size_t)row*HID + k0);
#pragma unroll
            for (int nf = 0; nf < 4; ++nf) {
                acc[mf][nf] = __builtin_amdgcn_mfma_f32_16x16x32_bf16(ah, bfr[nf], acc[mf][nf], 0,0,0);
                acc[mf][nf] = __builtin_amdgcn_mfma_f32_16x16x32_bf16(al, bfr[nf], acc[mf][nf], 0,0,0);
            }
        }
    }
    float* ob = out + (size_t)b * CIN * NPX;
#pragma unroll
    for (int mf = 0; mf < 3; ++mf)
#pragma unroll
        for (int nf = 0; nf < 4; ++nf)
#pragma unroll
            for (int r = 0; r < 4; ++r) {
                int oc = ms*48 + mf*16 + g4*4 + r;
                ob[(size_t)oc * NPX + px0 + nf*16 + lm] = acc[mf][nf][r];
            }
}

// ---------------------------------------------------------------------------
extern "C" void kernel_launch(void* const* d_in, const int* in_sizes, int n_in,
                              void* d_out, int out_size, void* d_ws, size_t ws_size,
                              hipStream_t stream) {
    const float* x     = (const float*)d_in[0];
    const float* w_in  = (const float*)d_in[1];
    const float* w_dw  = (const float*)d_in[2];
    const float* fftw  = (const float*)d_in[3];
    const float* w_out = (const float*)d_in[4];
    float* out = (float*)d_out;

    char* ws = (char*)d_ws;
    ushort* whi_in  = (ushort*)(ws + 0);        //  73728
    ushort* wlo_in  = (ushort*)(ws + 73728);    //  73728
    ushort* whi_out = (ushort*)(ws + 147456);   //  36864
    ushort* wlo_out = (ushort*)(ws + 184320);   //  36864
    float*  g       = (float*) (ws + 221184);   //  98304
    int*    flags   = (int*)   (ws + 319488);   //   1536
    __hip_bfloat16* z = (__hip_bfloat16*)(ws + 327680);   // 50331648 (one batch)
    ushort* tgf     = (ushort*)(ws + 50659328);           // up to 25165824

    // t_g chunk rows (multiple of 16) that fit in remaining workspace
    size_t avail = (ws_size > 50659328u) ? (ws_size - 50659328u) : 0u;
    long long nrl = (long long)(avail / 98304u);   // bytes per image row of tgf
    int nr = (int)((nrl / 16) * 16);
    if (nr < 16) nr = 16;
    if (nr > 256) nr = 256;

    prep_gate<<<dim3(C2), dim3(64), 0, stream>>>(fftw, g, flags);
    prep_w<<<dim3(216), dim3(256), 0, stream>>>(w_in, w_out,
                                                whi_in, wlo_in, whi_out, wlo_out);

    for (int b = 0; b < B_; ++b) {
        gemm1_mfma<<<dim3(NPX/64), dim3(256), 0, stream>>>(x, whi_in, wlo_in, z, b);
        gate_fix<<<dim3(HP*WP), dim3(256), 0, stream>>>(z, g, flags);
        for (int r0 = 0; r0 < H_; r0 += nr) {
            int rows = (H_ - r0 < nr) ? (H_ - r0) : nr;
            dw_gelu<<<dim3(16*(rows/16), 4), dim3(256), 0, stream>>>(z, w_dw, tgf, r0);
            gemm2_mfma<<<dim3(rows, 2), dim3(256), 0, stream>>>(tgf, whi_out, wlo_out,
                                                                out, b, r0);
        }
    }
}

// Round 3
// 373.423 us; speedup vs baseline: 6.9117x; 1.3711x over previous
//
#include <hip/hip_runtime.h>
#include <hip/hip_bf16.h>
#include <math.h>

typedef short bf16x8 __attribute__((ext_vector_type(8)));
typedef float f32x4  __attribute__((ext_vector_type(4)));

constexpr int B_=4, CIN=96, H_=256, W_=256, HID=192, C2=384;
constexpr int NPX = H_*W_;          // 65536 px per (b,c) plane
#define PB 8
constexpr int HP = H_/PB, WP = W_/PB;

__device__ __forceinline__ ushort f2bf(float f) {
    __hip_bfloat16 h = __float2bfloat16(f);
    ushort u; __builtin_memcpy(&u, &h, 2); return u;
}
__device__ __forceinline__ float bf2f(ushort u) {
    __hip_bfloat16 h; __builtin_memcpy(&h, &u, 2); return __bfloat162float(h);
}

// Fast exact-erf GELU: A&S 7.1.26 rational approx, |err| <= ~2e-7 abs.
__device__ __forceinline__ float gelu_f(float x) {
    float u  = x * 0.70710678118654752f;
    float au = fabsf(u);
    float t  = __builtin_amdgcn_rcpf(fmaf(0.3275911f, au, 1.0f));
    float poly = t * fmaf(t, fmaf(t, fmaf(t, fmaf(t, 1.061405429f,
                     -1.453152027f), 1.421413741f), -0.284496736f),
                     0.254829592f);
    float e  = __builtin_amdgcn_exp2f(au * au * -1.4426950408889634f);
    float g  = fmaf(-poly, e, 1.0f);          // erf(|u|)
    float one_plus = 1.0f + copysignf(g, u);  // 1 + erf(u)
    return 0.5f * x * one_plus;
}

// ---------------------------------------------------------------------------
// prep_gate: per-channel 8x8 spatial gate kernel from fft_w (+identity flags).
// ---------------------------------------------------------------------------
__global__ void prep_gate(const float* __restrict__ fftw,
                          float* __restrict__ g, int* __restrict__ flags) {
    int c = blockIdx.x;
    int t = threadIdx.x;             // one wave
    int n1 = t >> 3, n2 = t & 7;
    const float* Wc = fftw + c * 40;
    const double ct[8] = {1.0, 0.70710678118654752, 0.0, -0.70710678118654752,
                          -1.0, -0.70710678118654752, 0.0, 0.70710678118654752};
    double acc = 0.0;
    for (int k1 = 0; k1 < 8; ++k1)
        for (int k2 = 0; k2 < 8; ++k2) {
            double geff;
            if (k2 == 0 || k2 == 4)
                geff = 0.5 * ((double)Wc[k1*5+k2] + (double)Wc[((8-k1)&7)*5+k2]);
            else if (k2 < 4) geff = (double)Wc[k1*5+k2];
            else             geff = (double)Wc[((8-k1)&7)*5 + (8-k2)];
            acc += geff * ct[(k1*n1 + k2*n2) & 7];
        }
    acc *= (1.0/64.0);
    g[c*64 + t] = (float)acc;
    double expect = (t == 0) ? 1.0 : 0.0;
    unsigned long long m = __ballot(fabs(acc - expect) <= 1e-6);
    if (t == 0) flags[c] = (m == 0xFFFFFFFFFFFFFFFFull) ? 1 : 0;
}

// Reduce flags -> single allflag word (gate_fix early-exit).
__global__ void reduce_flags(const int* __restrict__ flags,
                             int* __restrict__ allflag) {
    int t = threadIdx.x;             // 64
    int ok = 1;
    for (int j = t; j < C2; j += 64) ok &= flags[j];
    unsigned long long m = __ballot(ok != 0);
    if (t == 0) allflag[0] = (m == 0xFFFFFFFFFFFFFFFFull) ? 1 : 0;
}

// ---------------------------------------------------------------------------
// prep_w: split weights into bf16 hi + lo (residual) pairs.
// ---------------------------------------------------------------------------
__global__ void prep_w(const float* __restrict__ w_in, const float* __restrict__ w_out,
                       ushort* __restrict__ whi_in,  ushort* __restrict__ wlo_in,
                       ushort* __restrict__ whi_out, ushort* __restrict__ wlo_out) {
    int idx = blockIdx.x * 256 + threadIdx.x;
    if (idx < C2*CIN) {
        float v = w_in[idx];
        ushort h = f2bf(v);
        whi_in[idx] = h;
        wlo_in[idx] = f2bf(v - bf2f(h));
    }
    int j = idx - C2*CIN;
    if (j >= 0 && j < CIN*HID) {
        float v = w_out[j];
        ushort h = f2bf(v);
        whi_out[j] = h;
        wlo_out[j] = f2bf(v - bf2f(h));
    }
}

// ---------------------------------------------------------------------------
// A1: GEMM1 via MFMA 16x16x32 bf16.  z[c][px] = sum_k w_in[c][k] * x[k][px]
// ---------------------------------------------------------------------------
__global__ __launch_bounds__(256)
void gemm1_mfma(const float* __restrict__ x,
                const ushort* __restrict__ whi, const ushort* __restrict__ wlo,
                __hip_bfloat16* __restrict__ z, int b) {
    int t = threadIdx.x;
    int l = t & 63, wv = t >> 6;
    int lm = l & 15, g4 = l >> 4;
    int px0 = blockIdx.x * 64;
    const float* xb = x + (size_t)b * CIN * NPX;

    f32x4 acc[6][4];
#pragma unroll
    for (int mf = 0; mf < 6; ++mf)
#pragma unroll
        for (int nf = 0; nf < 4; ++nf) acc[mf][nf] = (f32x4){0.f,0.f,0.f,0.f};

#pragma unroll
    for (int kc = 0; kc < 3; ++kc) {
        int k0 = kc*32 + g4*8;
        bf16x8 bfr[4];
#pragma unroll
        for (int nf = 0; nf < 4; ++nf) {
            const float* xp = xb + (size_t)k0 * NPX + px0 + nf*16 + lm;
            bf16x8 v;
#pragma unroll
            for (int j = 0; j < 8; ++j) v[j] = (short)f2bf(xp[(size_t)j * NPX]);
            bfr[nf] = v;
        }
#pragma unroll
        for (int mf = 0; mf < 6; ++mf) {
            int row = wv*96 + mf*16 + lm;
            bf16x8 ah = *(const bf16x8*)(whi + (size_t)row*CIN + k0);
            bf16x8 al = *(const bf16x8*)(wlo + (size_t)row*CIN + k0);
#pragma unroll
            for (int nf = 0; nf < 4; ++nf) {
                acc[mf][nf] = __builtin_amdgcn_mfma_f32_16x16x32_bf16(ah, bfr[nf], acc[mf][nf], 0,0,0);
                acc[mf][nf] = __builtin_amdgcn_mfma_f32_16x16x32_bf16(al, bfr[nf], acc[mf][nf], 0,0,0);
            }
        }
    }
#pragma unroll
    for (int mf = 0; mf < 6; ++mf)
#pragma unroll
        for (int nf = 0; nf < 4; ++nf)
#pragma unroll
            for (int r = 0; r < 4; ++r) {
                int c = wv*96 + mf*16 + g4*4 + r;
                z[(size_t)c * NPX + px0 + nf*16 + lm] =
                    __float2bfloat16(acc[mf][nf][r]);
            }
}

// ---------------------------------------------------------------------------
// A2: spectral-gate fixup. No-op when allflag (fft_w == ones).
// ---------------------------------------------------------------------------
__global__ __launch_bounds__(256)
void gate_fix(__hip_bfloat16* __restrict__ z, const float* __restrict__ g,
              const int* __restrict__ flags, const int* __restrict__ allflag) {
    if (allflag[0]) return;
    int pid = blockIdx.x;            // 0..1023 patches
    int ph = pid >> 5, pw = pid & 31;
    int t = threadIdx.x, l = t & 63, wv = t >> 6;
    int p1 = l >> 3, p2 = l & 7;
    size_t base = (size_t)(ph*8) * W_ + pw*8;
    for (int c = wv; c < C2; c += 4) {
        if (flags[c]) continue;
        const float* gc = g + c*64;
        size_t zi = (size_t)c * NPX + base + (size_t)p1 * W_ + p2;
        float v = __bfloat162float(z[zi]);
        float s = 0.f;
        for (int q = 0; q < 64; ++q) {
            float vq = __shfl(v, q, 64);
            s += vq * gc[((p1 - (q >> 3)) & 7)*8 + ((p2 - (q & 7)) & 7)];
        }
        z[zi] = __float2bfloat16(s);
    }
}

// ---------------------------------------------------------------------------
// B1 v2: depthwise 3x3 + fast exact-erf GELU gating.
// Block: 256 thr, full-width strip 256x4 px; channel split = 8 consecutive
// pairs (c0..c0+7, +192).  Halo = 6 full rows -> perfectly coalesced 16B
// staging, zero line waste.  Output packed directly in MFMA-B-frag layout:
// tgf[panel][kc][lane][8 bf16].
// Grid: (rows/4, 24).
// ---------------------------------------------------------------------------
__global__ __launch_bounds__(256)
void dw_gelu2(const __hip_bfloat16* __restrict__ z,
              const float* __restrict__ w_dw,
              ushort* __restrict__ tgf, int r0) {
    __shared__ ushort sZ[2][2][6][272];   // [buf][ch-half][halo row][8+256+8]
    int t = threadIdx.x;
    int wv = t >> 6;                      // output row within strip 0..3
    int lane = t & 63;
    int cb = lane * 4;                    // output col base (4 px per thread)
    int strip = blockIdx.x;
    int s = blockIdx.y;                   // 0..23 -> channels c0 = 8s
    int c0 = s * 8;
    int row0 = r0 + strip * 4;

    // zero entire LDS once (pads + OOB rows stay zero forever)
    {
        uint* sf = (uint*)&sZ[0][0][0][0];
        for (int i = t; i < 2*2*6*272/2; i += 256) sf[i] = 0u;
    }

    auto stage = [&](int ci, int bi) {
        // 2ch x 6 rows x 32 vectors(8 px) = 384 vec loads over 256 threads
        for (int v = t; v < 384; v += 256) {
            int ch  = (v >= 192) ? 1 : 0;
            int rem = v - ch * 192;
            int row = rem >> 5;
            int vx  = rem & 31;
            int y   = row0 - 1 + row;
            if (y >= 0 && y < H_) {
                int c = c0 + ci + ch * HID;
                uint4 val = *(const uint4*)(z + (size_t)c * NPX +
                                            (size_t)y * W_ + vx * 8);
                *(uint4*)&sZ[bi][ch][row][8 + vx * 8] = val;
            }
        }
    };

    uint pk[4][4];                        // [px j][channel word]

    stage(0, 0);
#pragma unroll
    for (int i = 0; i < 8; ++i) {
        int cur = i & 1;
        __syncthreads();
        if (i < 7) stage(i + 1, cur ^ 1);
        int c = c0 + i;
        const float* wd1 = w_dw + c * 9;
        const float* wd2 = w_dw + (c + HID) * 9;
        float d1[4] = {0.f,0.f,0.f,0.f};
        float d2[4] = {0.f,0.f,0.f,0.f};
#pragma unroll
        for (int dr = 0; dr < 3; ++dr) {
            const ushort* r1 = &sZ[cur][0][wv + dr][0];
            const ushort* r2 = &sZ[cur][1][wv + dr][0];
            int base = 8 + cb;
            float a0 = bf2f(r1[base - 1]);
            float a1 = bf2f(r1[base + 0]);
            float a2 = bf2f(r1[base + 1]);
            float a3 = bf2f(r1[base + 2]);
            float a4 = bf2f(r1[base + 3]);
            float a5 = bf2f(r1[base + 4]);
            float b0 = bf2f(r2[base - 1]);
            float b1 = bf2f(r2[base + 0]);
            float b2 = bf2f(r2[base + 1]);
            float b3 = bf2f(r2[base + 2]);
            float b4 = bf2f(r2[base + 3]);
            float b5 = bf2f(r2[base + 4]);
            float w10 = wd1[dr*3+0], w11 = wd1[dr*3+1], w12 = wd1[dr*3+2];
            float w20 = wd2[dr*3+0], w21 = wd2[dr*3+1], w22 = wd2[dr*3+2];
            d1[0] = fmaf(a0,w10, fmaf(a1,w11, fmaf(a2,w12, d1[0])));
            d1[1] = fmaf(a1,w10, fmaf(a2,w11, fmaf(a3,w12, d1[1])));
            d1[2] = fmaf(a2,w10, fmaf(a3,w11, fmaf(a4,w12, d1[2])));
            d1[3] = fmaf(a3,w10, fmaf(a4,w11, fmaf(a5,w12, d1[3])));
            d2[0] = fmaf(b0,w20, fmaf(b1,w21, fmaf(b2,w22, d2[0])));
            d2[1] = fmaf(b1,w20, fmaf(b2,w21, fmaf(b3,w22, d2[1])));
            d2[2] = fmaf(b2,w20, fmaf(b3,w21, fmaf(b4,w22, d2[2])));
            d2[3] = fmaf(b3,w20, fmaf(b4,w21, fmaf(b5,w22, d2[3])));
        }
#pragma unroll
        for (int j = 0; j < 4; ++j) {
            ushort u = f2bf(gelu_f(d1[j]) * d2[j]);
            if ((i & 1) == 0) pk[j][i >> 1] = (uint)u;
            else              pk[j][i >> 1] |= ((uint)u) << 16;
        }
    }

    // write 4 px x 8 channels in MFMA-B-frag layout
    int kc = c0 >> 5;
    int gg = (c0 & 31) >> 3;
    int prow = strip * 4 + wv;            // row within chunk
#pragma unroll
    for (int j = 0; j < 4; ++j) {
        int pidx = prow * W_ + cb + j;
        int panel = pidx >> 4, lm = pidx & 15;
        uint4 val; val.x = pk[j][0]; val.y = pk[j][1];
        val.z = pk[j][2]; val.w = pk[j][3];
        *(uint4*)(tgf + (size_t)((panel * 6 + kc) * 64 + gg * 16 + lm) * 8) = val;
    }
}

// ---------------------------------------------------------------------------
// B2: GEMM2 via MFMA.  out[oc][px] = sum_c w_out[oc][c] * t_g[c][px]
// ---------------------------------------------------------------------------
__global__ __launch_bounds__(256)
void gemm2_mfma(const ushort* __restrict__ tgf,
                const ushort* __restrict__ whi, const ushort* __restrict__ wlo,
                float* __restrict__ out, int b, int r0) {
    int t = threadIdx.x;
    int l = t & 63, wv = t >> 6;
    int lm = l & 15, g4 = l >> 4;
    int h = r0 + blockIdx.x;
    int ms = blockIdx.y;             // 0/1 -> oc base 0/48
    int px0 = h * W_ + wv*64;
    int prel0 = (h - r0)*16 + wv*4;

    f32x4 acc[3][4];
#pragma unroll
    for (int mf = 0; mf < 3; ++mf)
#pragma unroll
        for (int nf = 0; nf < 4; ++nf) acc[mf][nf] = (f32x4){0.f,0.f,0.f,0.f};

#pragma unroll
    for (int kc = 0; kc < 6; ++kc) {
        bf16x8 bfr[4];
#pragma unroll
        for (int nf = 0; nf < 4; ++nf)
            bfr[nf] = *(const bf16x8*)(tgf + (size_t)(((prel0+nf)*6 + kc)*64 + l) * 8);
        int k0 = kc*32 + g4*8;
#pragma unroll
        for (int mf = 0; mf < 3; ++mf) {
            int row = ms*48 + mf*16 + lm;
            bf16x8 ah = *(const bf16x8*)(whi + (size_t)row*HID + k0);
            bf16x8 al = *(const bf16x8*)(wlo + (size_t)row*HID + k0);
#pragma unroll
            for (int nf = 0; nf < 4; ++nf) {
                acc[mf][nf] = __builtin_amdgcn_mfma_f32_16x16x32_bf16(ah, bfr[nf], acc[mf][nf], 0,0,0);
                acc[mf][nf] = __builtin_amdgcn_mfma_f32_16x16x32_bf16(al, bfr[nf], acc[mf][nf], 0,0,0);
            }
        }
    }
    float* ob = out + (size_t)b * CIN * NPX;
#pragma unroll
    for (int mf = 0; mf < 3; ++mf)
#pragma unroll
        for (int nf = 0; nf < 4; ++nf)
#pragma unroll
            for (int r = 0; r < 4; ++r) {
                int oc = ms*48 + mf*16 + g4*4 + r;
                ob[(size_t)oc * NPX + px0 + nf*16 + lm] = acc[mf][nf][r];
            }
}

// ---------------------------------------------------------------------------
extern "C" void kernel_launch(void* const* d_in, const int* in_sizes, int n_in,
                              void* d_out, int out_size, void* d_ws, size_t ws_size,
                              hipStream_t stream) {
    const float* x     = (const float*)d_in[0];
    const float* w_in  = (const float*)d_in[1];
    const float* w_dw  = (const float*)d_in[2];
    const float* fftw  = (const float*)d_in[3];
    const float* w_out = (const float*)d_in[4];
    float* out = (float*)d_out;

    char* ws = (char*)d_ws;
    ushort* whi_in  = (ushort*)(ws + 0);        //  73728
    ushort* wlo_in  = (ushort*)(ws + 73728);    //  73728
    ushort* whi_out = (ushort*)(ws + 147456);   //  36864
    ushort* wlo_out = (ushort*)(ws + 184320);   //  36864
    float*  g       = (float*) (ws + 221184);   //  98304
    int*    flags   = (int*)   (ws + 319488);   //   1536
    int*    allflag = (int*)   (ws + 321024);   //      4
    __hip_bfloat16* z = (__hip_bfloat16*)(ws + 327680);   // 50331648 (one batch)
    ushort* tgf     = (ushort*)(ws + 50659328);           // up to 25165824

    // t_g chunk rows (multiple of 16) that fit in remaining workspace
    size_t avail = (ws_size > 50659328u) ? (ws_size - 50659328u) : 0u;
    long long nrl = (long long)(avail / 98304u);   // bytes per image row of tgf
    int nr = (int)((nrl / 16) * 16);
    if (nr < 16) nr = 16;
    if (nr > 256) nr = 256;

    prep_gate<<<dim3(C2), dim3(64), 0, stream>>>(fftw, g, flags);
    reduce_flags<<<dim3(1), dim3(64), 0, stream>>>(flags, allflag);
    prep_w<<<dim3(216), dim3(256), 0, stream>>>(w_in, w_out,
                                                whi_in, wlo_in, whi_out, wlo_out);

    for (int b = 0; b < B_; ++b) {
        gemm1_mfma<<<dim3(NPX/64), dim3(256), 0, stream>>>(x, whi_in, wlo_in, z, b);
        gate_fix<<<dim3(HP*WP), dim3(256), 0, stream>>>(z, g, flags, allflag);
        for (int r0 = 0; r0 < H_; r0 += nr) {
            int rows = (H_ - r0 < nr) ? (H_ - r0) : nr;
            dw_gelu2<<<dim3(rows/4, 24), dim3(256), 0, stream>>>(z, w_dw, tgf, r0);
            gemm2_mfma<<<dim3(rows, 2), dim3(256), 0, stream>>>(tgf, whi_out, wlo_out,
                                                                out, b, r0);
        }
    }
}